// Round 8
// baseline (285.935 us; speedup 1.0000x reference)
//
#include <hip/hip_runtime.h>
#include <cstdint>
#include <cstddef>

#define D 128
#define F_IN 256

typedef __attribute__((ext_vector_type(8))) short bf16x8;
typedef __attribute__((ext_vector_type(4))) float f32x4;

__device__ __forceinline__ unsigned short f2bs(float f) {
  unsigned int x = __builtin_bit_cast(unsigned int, f);
  x = x + 0x7fffu + ((x >> 16) & 1u);           // round-to-nearest-even
  return (unsigned short)(x >> 16);
}
__device__ __forceinline__ unsigned pk2(float lo, float hi) {
  return (unsigned)f2bs(lo) | ((unsigned)f2bs(hi) << 16);
}
__device__ __forceinline__ float b2f(unsigned int lo16) {
  unsigned int x = lo16 << 16;
  return __builtin_bit_cast(float, x);
}
__device__ __forceinline__ void gl_lds16v(const void* g, void* l) {
  __builtin_amdgcn_global_load_lds(
      (__attribute__((address_space(1))) void*)g,
      (__attribute__((address_space(3))) void*)l, 16, 0, 0);
}
__device__ __forceinline__ uint4 pack8(float4 a, float4 b) {
  uint4 o;
  o.x = pk2(a.x, a.y); o.y = pk2(a.z, a.w);
  o.z = pk2(b.x, b.y); o.w = pk2(b.z, b.w);
  return o;
}

// ================= prep: weight converts + prof gather + bucket histogram =================

__global__ __launch_bounds__(256) void prep_k(
    const float* __restrict__ s0, unsigned short* __restrict__ d0, int n0,
    const float* __restrict__ s1, unsigned short* __restrict__ d1, int n1,
    const float* __restrict__ s2, unsigned short* __restrict__ d2, int n2,
    const float* __restrict__ s3, unsigned short* __restrict__ d3, int n3,
    const float* __restrict__ s4, unsigned short* __restrict__ d4, int n4,
    int nbC,
    const float* __restrict__ emb, const int* __restrict__ ids,
    unsigned short* __restrict__ hm, int NM, int nbG,
    const int* __restrict__ esrc, const int* __restrict__ edst,
    int* __restrict__ bktT, int* __restrict__ bktM,
    int E, int SHT, int SHM, int nbA)
{
  int bid = blockIdx.x;
  int tid = threadIdx.x;
  if (bid < nbC) {
    int j = bid * 256 + tid;
    const float* s; unsigned short* d;
    if (j < n0) { s = s0; d = d0; }
    else {
      j -= n0;
      if (j < n1) { s = s1; d = d1; }
      else {
        j -= n1;
        if (j < n2) { s = s2; d = d2; }
        else {
          j -= n2;
          if (j < n3) { s = s3; d = d3; }
          else { j -= n3; if (j >= n4) return; s = s4; d = d4; }
        }
      }
    }
    const float4* sp = (const float4*)(s + (size_t)j * 8);
    *(uint4*)(d + (size_t)j * 8) = pack8(sp[0], sp[1]);
    return;
  }
  bid -= nbC;
  if (bid < nbG) {
    int i = bid * 256 + tid;
    if (i >= NM * 16) return;
    int r = i >> 4, c = (i & 15) * 8;
    const float* s = emb + (size_t)ids[r] * D + c;
    *(uint4*)(hm + (size_t)r * D + c) = pack8(*(const float4*)s, *(const float4*)(s + 4));
    return;
  }
  bid -= nbG;
  __shared__ int sh[256];
  sh[tid] = 0;
  __syncthreads();
  int stride = nbA * 256;
  for (int e = bid * 256 + tid; e < E; e += stride) {
    atomicAdd(&sh[esrc[e] >> SHT], 1);
    atomicAdd(&sh[128 + (edst[e] >> SHM)], 1);
  }
  __syncthreads();
  if (tid < 128) { if (sh[tid]) atomicAdd(&bktT[tid], sh[tid]); }
  else { if (sh[tid]) atomicAdd(&bktM[tid - 128], sh[tid]); }
}

// ================= A2: scan bucket counts -> bases + cursors =================

__global__ void a2_scan_k(const int* __restrict__ bktT, int* __restrict__ baseT, int* __restrict__ curT, int BT,
                          const int* __restrict__ bktM, int* __restrict__ baseM, int* __restrict__ curM, int BM) {
  __shared__ int sT[129], sM[129];
  int tid = threadIdx.x;
  if (tid < BT) sT[tid] = bktT[tid];
  if (tid < BM) sM[tid] = bktM[tid];
  __syncthreads();
  if (tid == 0) { int r = 0; for (int i = 0; i < BT; ++i) { int c = sT[i]; sT[i] = r; r += c; } sT[BT] = r; }
  if (tid == 1) { int r = 0; for (int i = 0; i < BM; ++i) { int c = sM[i]; sM[i] = r; r += c; } sM[BM] = r; }
  __syncthreads();
  if (tid <= BT) { baseT[tid] = sT[tid]; if (tid < BT) curT[tid] = sT[tid]; }
  if (tid <= BM) { baseM[tid] = sM[tid]; if (tid < BM) curM[tid] = sM[tid]; }
}

// ================= A3: multi-split partition with LDS staging =================

#define CH 4096

__global__ __launch_bounds__(256) void a3_part_k(
    const int* __restrict__ esrc, const int* __restrict__ edst,
    unsigned* __restrict__ partT, unsigned* __restrict__ partM,
    int* __restrict__ curT, int* __restrict__ curM,
    int E, int BT, int BM, int SHT, int SHM)
{
  __shared__ unsigned stT[CH], stM[CH];
  __shared__ int hT[128], lbT[128], lcT[128], gbT[128];
  __shared__ int hM[128], lbM[128], lcM[128], gbM[128];
  __shared__ int st2[256];
  int tid = threadIdx.x;
  int c0 = blockIdx.x * CH;
  int len = E - c0; if (len > CH) len = CH;

  if (tid < 128) { hT[tid] = 0; hM[tid] = 0; }
  __syncthreads();
  for (int i = tid; i < len; i += 256) {
    atomicAdd(&hT[esrc[c0 + i] >> SHT], 1);
    atomicAdd(&hM[edst[c0 + i] >> SHM], 1);
  }
  __syncthreads();
  int own = (tid < 128) ? hT[tid] : hM[tid - 128];
  st2[tid] = own;
  __syncthreads();
  for (int dd = 1; dd < 128; dd <<= 1) {
    int y = ((tid & 127) >= dd) ? st2[tid - dd] : 0;
    __syncthreads();
    st2[tid] += y;
    __syncthreads();
  }
  int excl = st2[tid] - own;
  if (tid < 128) { lbT[tid] = excl; lcT[tid] = excl; }
  else { lbM[tid - 128] = excl; lcM[tid - 128] = excl; }
  __syncthreads();
  if (tid < BT) { if (hT[tid]) gbT[tid] = atomicAdd(&curT[tid], hT[tid]); }
  if (tid >= 128 && tid - 128 < BM) { int m = tid - 128; if (hM[m]) gbM[m] = atomicAdd(&curM[m], hM[m]); }
  __syncthreads();
  for (int i = tid; i < len; i += 256) {
    unsigned s = (unsigned)esrc[c0 + i], dn = (unsigned)edst[c0 + i];
    int p = atomicAdd(&lcT[s >> SHT], 1);
    stT[p] = (s << 15) | dn;
    int q = atomicAdd(&lcM[dn >> SHM], 1);
    stM[q] = (dn << 17) | s;
  }
  __syncthreads();
  for (int b = 0; b < BT; ++b) {
    int cb = hT[b]; if (!cb) continue;
    int lb = lbT[b]; int gb = gbT[b];
    for (int i = tid; i < cb; i += 256) partT[gb + i] = stT[lb + i];
  }
  for (int b = 0; b < BM; ++b) {
    int cb = hM[b]; if (!cb) continue;
    int lb = lbM[b]; int gb = gbM[b];
    for (int i = tid; i < cb; i += 256) partM[gb + i] = stM[lb + i];
  }
}

// ================= B: per-bucket CSR finalize (rowptr, csr) =================

#define BCAP 12288

__global__ __launch_bounds__(256) void b_csr_k(
    const unsigned* __restrict__ partT, const int* __restrict__ baseT,
    int* __restrict__ rowT, int* __restrict__ csrT, int NT, int BT, int SHT,
    const unsigned* __restrict__ partM, const int* __restrict__ baseM,
    int* __restrict__ rowM, int* __restrict__ csrM, int NM, int BM, int SHM, int E)
{
  __shared__ int cnt[1024];
  __shared__ int st[256];
  __shared__ unsigned stage[BCAP];

  const unsigned* part; const int* base; int* row; int* csr;
  int N, SH, KS; unsigned PM; int b; bool last;
  if ((int)blockIdx.x < BT) {
    part = partT; base = baseT; row = rowT; csr = csrT;
    N = NT; SH = SHT; KS = 15; PM = 0x7fffu; b = blockIdx.x; last = (b == BT - 1);
  } else {
    part = partM; base = baseM; row = rowM; csr = csrM;
    N = NM; SH = SHM; KS = 17; PM = 0x1ffffu; b = blockIdx.x - BT; last = (b == BM - 1);
  }
  int tid = threadIdx.x;
  int ebeg = base[b], eend = base[b + 1];
  int tot = eend - ebeg;
  int n0 = b << SH;
  int width = 1 << SH;
  int nw = N - n0; if (nw > width) nw = width;
  int seg = (width + 255) >> 8;

  for (int j = 0; j < seg; ++j) { int idx = tid * seg + j; if (idx < nw) cnt[idx] = 0; }
  __syncthreads();
  for (int i = tid; i < tot; i += 256) {
    int k = (int)(part[ebeg + i] >> KS) - n0;
    atomicAdd(&cnt[k], 1);
  }
  __syncthreads();
  int s = 0;
  for (int j = 0; j < seg; ++j) { int idx = tid * seg + j; if (idx < nw) s += cnt[idx]; }
  st[tid] = s;
  __syncthreads();
  for (int dd = 1; dd < 256; dd <<= 1) {
    int y = (tid >= dd) ? st[tid - dd] : 0;
    __syncthreads();
    st[tid] += y;
    __syncthreads();
  }
  int run = st[tid] - s;
  for (int j = 0; j < seg; ++j) {
    int idx = tid * seg + j;
    if (idx < nw) {
      int c = cnt[idx];
      row[n0 + idx] = ebeg + run;
      cnt[idx] = run;
      run += c;
    }
  }
  if (last && tid == 0) row[N] = E;
  __syncthreads();
  if (tot <= BCAP) {
    for (int i = tid; i < tot; i += 256) {
      unsigned p = part[ebeg + i];
      int k = (int)(p >> KS) - n0;
      int pos = atomicAdd(&cnt[k], 1);
      stage[pos] = p & PM;
    }
    __syncthreads();
    for (int i = tid; i < tot; i += 256) csr[ebeg + i] = (int)stage[i];
  } else {
    for (int i = tid; i < tot; i += 256) {
      unsigned p = part[ebeg + i];
      int k = (int)(p >> KS) - n0;
      int pos = atomicAdd(&cnt[k], 1);
      csr[ebeg + pos] = (int)(p & PM);
    }
  }
}

// ================= fused layer: aggregate (into LDS) + dual GEMM =================
// 64 nodes per block. LDS: agg tile [64][128] bf16 (16KB, XOR-swizzled) +
// W chunk [128][32] (8KB) + root chunk [64][32] (4KB). out = agg@Wn^T + root@Wr^T + bias.

template<bool RELU>
__device__ __forceinline__ void layer_body(
    const unsigned short* __restrict__ tab, const int* __restrict__ rowp,
    const int* __restrict__ idx, const unsigned short* __restrict__ root,
    const unsigned short* __restrict__ Wn, const unsigned short* __restrict__ Wr,
    const float* __restrict__ bias, unsigned short* __restrict__ out,
    int n, int blk, char* smraw)
{
  unsigned short* aggp = (unsigned short*)smraw;             // [64][128] bf16
  unsigned short* wbuf = (unsigned short*)(smraw + 16384);   // [128][32]
  unsigned short* rbuf = (unsigned short*)(smraw + 24576);   // [64][32]
  const int tid = threadIdx.x;
  const int w = tid >> 6, l = tid & 63;
  const int g = tid >> 5;        // 32-lane group 0..7
  const int l32 = tid & 31;
  const int wr = w >> 1, wc = w & 1;
  const int lr = l & 15, kg = l >> 4;
  const int n0 = blk * 64;

  // ---- phase A: aggregate 8 nodes per group into LDS ----
  const unsigned short* tl = tab + l32 * 4;
  for (int i = 0; i < 8; ++i) {
    int r = g * 8 + i;
    int node = n0 + r;
    int nodeC = node < n ? node : n - 1;
    int b = rowp[nodeC];
    int e = rowp[nodeC + 1];
    if (node >= n) e = b;
    int deg = e - b;
    float a0 = 0.f, a1 = 0.f, a2 = 0.f, a3 = 0.f;
    int p = b;
    while (p + 8 <= e) {
      int nn[8];
#pragma unroll
      for (int u = 0; u < 8; ++u) nn[u] = idx[p + u];
      uint2 vv[8];
#pragma unroll
      for (int u = 0; u < 8; ++u) vv[u] = *(const uint2*)(tl + (size_t)nn[u] * D);
#pragma unroll
      for (int u = 0; u < 8; ++u) {
        a0 += b2f(vv[u].x & 0xffffu); a1 += b2f(vv[u].x >> 16);
        a2 += b2f(vv[u].y & 0xffffu); a3 += b2f(vv[u].y >> 16);
      }
      p += 8;
    }
    if (p + 4 <= e) {
      int nn[4];
#pragma unroll
      for (int u = 0; u < 4; ++u) nn[u] = idx[p + u];
      uint2 vv[4];
#pragma unroll
      for (int u = 0; u < 4; ++u) vv[u] = *(const uint2*)(tl + (size_t)nn[u] * D);
#pragma unroll
      for (int u = 0; u < 4; ++u) {
        a0 += b2f(vv[u].x & 0xffffu); a1 += b2f(vv[u].x >> 16);
        a2 += b2f(vv[u].y & 0xffffu); a3 += b2f(vv[u].y >> 16);
      }
      p += 4;
    }
    {
      bool h0 = p < e, h1 = p + 1 < e, h2 = p + 2 < e;
      int m0 = h0 ? idx[p] : 0, m1 = h1 ? idx[p + 1] : 0, m2 = h2 ? idx[p + 2] : 0;
      uint2 w0 = make_uint2(0u, 0u), w1 = make_uint2(0u, 0u), w2 = make_uint2(0u, 0u);
      if (h0) w0 = *(const uint2*)(tl + (size_t)m0 * D);
      if (h1) w1 = *(const uint2*)(tl + (size_t)m1 * D);
      if (h2) w2 = *(const uint2*)(tl + (size_t)m2 * D);
      if (h0) { a0 += b2f(w0.x & 0xffffu); a1 += b2f(w0.x >> 16); a2 += b2f(w0.y & 0xffffu); a3 += b2f(w0.y >> 16); }
      if (h1) { a0 += b2f(w1.x & 0xffffu); a1 += b2f(w1.x >> 16); a2 += b2f(w1.y & 0xffffu); a3 += b2f(w1.y >> 16); }
      if (h2) { a0 += b2f(w2.x & 0xffffu); a1 += b2f(w2.x >> 16); a2 += b2f(w2.y & 0xffffu); a3 += b2f(w2.y >> 16); }
    }
    float inv = 1.0f / (float)(deg > 1 ? deg : 1);
    int u = (l32 >> 1) ^ (r & 7);                   // swizzled 16B unit (0..15)
    *(uint2*)(aggp + r * 128 + u * 8 + (l32 & 1) * 4) =
        make_uint2(pk2(a0 * inv, a1 * inv), pk2(a2 * inv, a3 * inv));
  }
  __syncthreads();

  // ---- phase B: dual GEMM, 8 K-chunks (4 agg@Wn + 4 root@Wr) ----
  f32x4 acc[2][4] = {};
  const int srow = l >> 2, su = l & 3;
#pragma unroll 1
  for (int ch = 0; ch < 8; ++ch) {
    if (ch) __syncthreads();
    {
      const unsigned short* Wp = (ch < 4) ? Wn : Wr;
      int k0 = (ch & 3) * 32;
#pragma unroll
      for (int q = 0; q < 2; ++q) {
        int r = w * 32 + q * 16 + srow;
        int gu = su ^ ((r >> 1) & 3);
        gl_lds16v(Wp + (size_t)r * D + k0 + gu * 8, wbuf + (w * 32 + q * 16) * 32 + l * 8);
      }
      if (ch >= 4) {
        int r = tid >> 2;                       // 0..63
        int gr = n0 + r; if (gr >= n) gr = n - 1;
        int gu = su ^ ((r >> 1) & 3);
        gl_lds16v(root + (size_t)gr * D + k0 + gu * 8, rbuf + r * 32 + su * 8);
      }
    }
    __syncthreads();                            // drains vmcnt before ds_read
    bf16x8 aF[2], bF[4];
    if (ch < 4) {
#pragma unroll
      for (int i = 0; i < 2; ++i) {
        int rr = wr * 32 + i * 16 + lr;
        int u = ((ch & 3) * 4 + kg) ^ (rr & 7);
        aF[i] = *(const bf16x8*)&aggp[rr * 128 + u * 8];
      }
    } else {
#pragma unroll
      for (int i = 0; i < 2; ++i) {
        int rr = wr * 32 + i * 16 + lr;
        aF[i] = *(const bf16x8*)&rbuf[rr * 32 + ((kg ^ ((rr >> 1) & 3)) * 8)];
      }
    }
#pragma unroll
    for (int j = 0; j < 4; ++j) {
      int r = wc * 64 + j * 16 + lr;
      bF[j] = *(const bf16x8*)&wbuf[r * 32 + ((kg ^ ((r >> 1) & 3)) * 8)];
    }
#pragma unroll
    for (int i = 0; i < 2; ++i)
#pragma unroll
      for (int j = 0; j < 4; ++j)
        acc[i][j] = __builtin_amdgcn_mfma_f32_16x16x32_bf16(aF[i], bF[j], acc[i][j], 0, 0, 0);
  }

  // ---- epilogue: bias (+relu), stage in agg tile, coalesced store ----
  __syncthreads();
  float bn[4];
#pragma unroll
  for (int j = 0; j < 4; ++j) bn[j] = bias[wc * 64 + j * 16 + lr];
#pragma unroll
  for (int i = 0; i < 2; ++i)
#pragma unroll
    for (int j = 0; j < 4; ++j) {
      f32x4 v = acc[i][j];
#pragma unroll
      for (int r = 0; r < 4; ++r) {
        float x = v[r] + bn[j];
        if (RELU) x = fmaxf(x, 0.f);
        aggp[(wr * 32 + i * 16 + kg * 4 + r) * 128 + wc * 64 + j * 16 + lr] = f2bs(x);
      }
    }
  __syncthreads();
  // store full [64][128] tile: 1024 16B-units  (round-6 bug: only 512 covered)
#pragma unroll
  for (int q = 0; q < 4; ++q) {
    int u = q * 256 + tid;
    int lrow = u >> 4;            // 0..63
    int cu = (u & 15) * 8;        // 0..120
    int gr = n0 + lrow;
    if (gr < n)
      *(uint4*)(out + (size_t)gr * D + cu) = *(const uint4*)&aggp[lrow * 128 + cu];
  }
}

template<bool RELU>
__global__ __launch_bounds__(256) void layer_k(
    const unsigned short* __restrict__ tabM, const int* __restrict__ rowpM,
    const int* __restrict__ idxM, const unsigned short* __restrict__ rootM,
    const unsigned short* __restrict__ WnM, const unsigned short* __restrict__ WrM,
    const float* __restrict__ biasM, unsigned short* __restrict__ outM, int nM, int nbm,
    const unsigned short* __restrict__ tabT, const int* __restrict__ rowpT,
    const int* __restrict__ idxT, const unsigned short* __restrict__ rootT,
    const unsigned short* __restrict__ WnT, const unsigned short* __restrict__ WrT,
    const float* __restrict__ biasT, unsigned short* __restrict__ outT, int nT)
{
  __shared__ char smraw[28672];
  if ((int)blockIdx.x < nbm)
    layer_body<RELU>(tabM, rowpM, idxM, rootM, WnM, WrM, biasM, outM, nM, blockIdx.x, smraw);
  else
    layer_body<RELU>(tabT, rowpT, idxT, rootT, WnT, WrT, biasT, outT, nT, blockIdx.x - nbm, smraw);
}

// ================= encoder GEMM (fp32 A staged raw, counted-vmcnt pipeline) =================

__global__ __launch_bounds__(256) void gemm_enc_k(
    const float* __restrict__ A, const unsigned short* __restrict__ W,
    const float* __restrict__ bias, unsigned short* __restrict__ out, int M)
{
  __shared__ char smraw[49152];
  float* bufA0 = (float*)smraw;                              // [2][4096] f32
  unsigned short* bufW0 = (unsigned short*)(smraw + 32768);  // [2][4096] bf16
  const int tid = threadIdx.x;
  const int w = tid >> 6, l = tid & 63;
  const int wr = w >> 1, wc = w & 1;
  const int lr = l & 15, kg = l >> 4;
  const int row0 = blockIdx.x * 128;
  const int arow = l >> 3;
  const int au = l & 7;
  const int wrow = l >> 2;
  const int wu = l & 3;

  f32x4 acc[4][4] = {};

  auto stage = [&](int st, int bsel) {
    int k0 = st * 32;
    float* bA = bufA0 + bsel * 4096;
    unsigned short* bW = bufW0 + bsel * 4096;
#pragma unroll
    for (int q = 0; q < 4; ++q) {
      int r = w * 32 + q * 8 + arow;
      int gr = row0 + r; if (gr >= M) gr = M - 1;
      int gu = au ^ (r & 7);
      gl_lds16v(A + (size_t)gr * F_IN + k0 + gu * 4, bA + (w * 32 + q * 8) * 32 + l * 4);
    }
#pragma unroll
    for (int q = 0; q < 2; ++q) {
      int r = w * 32 + q * 16 + wrow;
      int gu = wu ^ ((r >> 1) & 3);
      gl_lds16v(W + (size_t)r * F_IN + k0 + gu * 8, bW + (w * 32 + q * 16) * 32 + l * 8);
    }
  };

  stage(0, 0);
#pragma unroll 1
  for (int st = 0; st < F_IN / 32; ++st) {
    if (st < F_IN / 32 - 1) {
      stage(st + 1, (st + 1) & 1);
      __builtin_amdgcn_sched_barrier(0);
      asm volatile("s_waitcnt vmcnt(6)" ::: "memory");
    } else {
      __builtin_amdgcn_sched_barrier(0);
      asm volatile("s_waitcnt vmcnt(0)" ::: "memory");
    }
    __builtin_amdgcn_s_barrier();
    __builtin_amdgcn_sched_barrier(0);
    const float* bA = bufA0 + (st & 1) * 4096;
    const unsigned short* bW = bufW0 + (st & 1) * 4096;
    bf16x8 aF[4], bF[4];
#pragma unroll
    for (int i = 0; i < 4; ++i) {
      int r = wr * 64 + i * 16 + lr;
      const float4* pa = (const float4*)(bA + r * 32);
      float4 v0 = pa[(2 * kg) ^ (r & 7)];
      float4 v1 = pa[(2 * kg + 1) ^ (r & 7)];
      uint4 c = pack8(v0, v1);
      aF[i] = *(bf16x8*)&c;
    }
#pragma unroll
    for (int j = 0; j < 4; ++j) {
      int r = wc * 64 + j * 16 + lr;
      bF[j] = *(const bf16x8*)&bW[r * 32 + ((kg ^ ((r >> 1) & 3)) * 8)];
    }
#pragma unroll
    for (int i = 0; i < 4; ++i)
#pragma unroll
      for (int j = 0; j < 4; ++j)
        acc[i][j] = __builtin_amdgcn_mfma_f32_16x16x32_bf16(aF[i], bF[j], acc[i][j], 0, 0, 0);
    __builtin_amdgcn_sched_barrier(0);
    __builtin_amdgcn_s_barrier();
  }

  __syncthreads();
  float bn[4];
#pragma unroll
  for (int j = 0; j < 4; ++j) bn[j] = bias[wc * 64 + j * 16 + lr];
  unsigned short* ow = (unsigned short*)smraw + w * 4096;
#pragma unroll
  for (int i = 0; i < 4; ++i)
#pragma unroll
    for (int j = 0; j < 4; ++j) {
      f32x4 v = acc[i][j];
#pragma unroll
      for (int r = 0; r < 4; ++r)
        ow[(i * 16 + kg * 4 + r) * 64 + j * 16 + lr] = f2bs(v[r] + bn[j]);
    }
  __syncthreads();
#pragma unroll
  for (int q = 0; q < 8; ++q) {
    int u = q * 64 + l;
    int lrow = u >> 3;
    int cu = (u & 7) * 8;
    int gr = row0 + wr * 64 + lrow;
    if (gr < M)
      *(uint4*)(out + (size_t)gr * D + wc * 64 + cu) = *(const uint4*)&ow[lrow * 64 + cu];
  }
}

// ================= classifier =================

__global__ __launch_bounds__(256) void classify_k(
    const unsigned short* __restrict__ ht, const unsigned short* __restrict__ hm,
    const int* __restrict__ qs, const int* __restrict__ qd,
    const float* __restrict__ w, const float* __restrict__ bptr,
    float* __restrict__ out, int Q)
{
  int g = blockIdx.x * 8 + (threadIdx.x >> 5);
  if (g >= Q) return;
  int l = threadIdx.x & 31;
  const unsigned short* src = (l < 16)
      ? ht + (size_t)qs[g] * D + l * 8
      : hm + (size_t)qd[g] * D + (l - 16) * 8;
  uint4 v = *(const uint4*)src;
  const float* wp = w + l * 8;
  float acc = 0.f;
  acc += b2f(v.x & 0xffffu) * wp[0];
  acc += b2f(v.x >> 16)     * wp[1];
  acc += b2f(v.y & 0xffffu) * wp[2];
  acc += b2f(v.y >> 16)     * wp[3];
  acc += b2f(v.z & 0xffffu) * wp[4];
  acc += b2f(v.z >> 16)     * wp[5];
  acc += b2f(v.w & 0xffffu) * wp[6];
  acc += b2f(v.w >> 16)     * wp[7];
#pragma unroll
  for (int m = 16; m >= 1; m >>= 1) acc += __shfl_xor(acc, m, 64);
  if (l == 0) out[g] = acc + bptr[0];
}

// ================= launcher =================

extern "C" void kernel_launch(void* const* d_in, const int* in_sizes, int n_in,
                              void* d_out, int out_size, void* d_ws, size_t ws_size,
                              hipStream_t stream)
{
  const float* x_thesis = (const float*)d_in[0];
  const int*   mentor_id = (const int*)d_in[1];
  const int*   esrc = (const int*)d_in[2];
  const int*   edst = (const int*)d_in[3];
  const int*   qsrc = (const int*)d_in[4];
  const int*   qdst = (const int*)d_in[5];
  const float* lin_w = (const float*)d_in[6];
  const float* lin_b = (const float*)d_in[7];
  const float* prof  = (const float*)d_in[8];
  const float* Wn_sup = (const float*)d_in[9];
  const float* Wr_sup = (const float*)d_in[10];
  const float* b_sup  = (const float*)d_in[11];
  const float* Wn_rev = (const float*)d_in[12];
  const float* Wr_rev = (const float*)d_in[13];
  const float* b_rev  = (const float*)d_in[14];
  const float* cls_w  = (const float*)d_in[15];
  const float* cls_b  = (const float*)d_in[16];

  const int NT = in_sizes[0] / F_IN;
  const int NM = in_sizes[1];
  const int E  = in_sizes[2];
  const int Q  = in_sizes[4];
  const int L  = in_sizes[11] / D;

  int SHT = 0; while ((((NT - 1) >> SHT) + 1) > 128) ++SHT;
  int SHM = 0; while ((((NM - 1) >> SHM) + 1) > 128) ++SHM;
  const int BT = ((NT - 1) >> SHT) + 1;
  const int BM = ((NM - 1) >> SHM) + 1;

  char* wsb = (char*)d_ws;
  size_t off = 0;
  auto alloc = [&](size_t bytes) {
    void* p = wsb + off;
    off = (off + bytes + 255) & ~(size_t)255;
    return p;
  };
  unsigned short* h_t   = (unsigned short*)alloc((size_t)NT * D * 2);
  unsigned short* a_t   = (unsigned short*)alloc((size_t)NT * D * 2);
  unsigned short* h_m   = (unsigned short*)alloc((size_t)NM * D * 2);
  unsigned short* a_m   = (unsigned short*)alloc((size_t)NM * D * 2);
  unsigned short* linw_bf = (unsigned short*)alloc((size_t)D * F_IN * 2);
  unsigned short* wns_bf  = (unsigned short*)alloc((size_t)L * D * D * 2);
  unsigned short* wrs_bf  = (unsigned short*)alloc((size_t)L * D * D * 2);
  unsigned short* wnr_bf  = (unsigned short*)alloc((size_t)L * D * D * 2);
  unsigned short* wrr_bf  = (unsigned short*)alloc((size_t)L * D * D * 2);
  int* row_t = (int*)alloc(((size_t)NT + 1) * 4);
  int* row_m = (int*)alloc(((size_t)NM + 1) * 4);
  int* csr_t = (int*)alloc((size_t)E * 4);
  int* csr_m = (int*)alloc((size_t)E * 4);
  unsigned* partT = (unsigned*)alloc((size_t)E * 4);
  unsigned* partM = (unsigned*)alloc((size_t)E * 4);
  size_t bkt_off = off;
  int* bktT  = (int*)alloc(128 * 4);
  int* bktM  = (int*)alloc(128 * 4);
  size_t bkt_end = off;
  int* baseT = (int*)alloc(129 * 4);
  int* baseM = (int*)alloc(129 * 4);
  int* curT  = (int*)alloc(128 * 4);
  int* curM  = (int*)alloc(128 * 4);
  (void)n_in; (void)out_size; (void)ws_size;

  (void)hipMemsetAsync(wsb + bkt_off, 0, bkt_end - bkt_off, stream);

  {
    int n0 = D * F_IN / 8, nw = L * D * D / 8;
    int totc = n0 + 4 * nw;
    int nbC = (totc + 255) / 256;
    int nbG = (NM * 16 + 255) / 256;
    int nbA = 256;
    prep_k<<<nbC + nbG + nbA, 256, 0, stream>>>(
        lin_w, linw_bf, n0, Wn_sup, wns_bf, nw, Wr_sup, wrs_bf, nw,
        Wn_rev, wnr_bf, nw, Wr_rev, wrr_bf, nw, nbC,
        prof, mentor_id, h_m, NM, nbG,
        esrc, edst, bktT, bktM, E, SHT, SHM, nbA);
  }
  a2_scan_k<<<1, 256, 0, stream>>>(bktT, baseT, curT, BT, bktM, baseM, curM, BM);
  a3_part_k<<<(E + CH - 1) / CH, 256, 0, stream>>>(
      esrc, edst, partT, partM, curT, curM, E, BT, BM, SHT, SHM);
  b_csr_k<<<BT + BM, 256, 0, stream>>>(
      partT, baseT, row_t, csr_t, NT, BT, SHT,
      partM, baseM, row_m, csr_m, NM, BM, SHM, E);

  gemm_enc_k<<<(NT + 127) / 128, 256, 0, stream>>>(x_thesis, linw_bf, lin_b, h_t, NT);

  int nbm64 = (NM + 63) / 64, nbt64 = (NT + 63) / 64;
  for (int l = 0; l < L; ++l) {
    const unsigned short* wns = wns_bf + (size_t)l * D * D;
    const unsigned short* wrs = wrs_bf + (size_t)l * D * D;
    const unsigned short* wnr = wnr_bf + (size_t)l * D * D;
    const unsigned short* wrr = wrr_bf + (size_t)l * D * D;
    const float* bs = b_sup + (size_t)l * D;
    const float* br = b_rev + (size_t)l * D;
    if (l < L - 1) {
      layer_k<true><<<nbm64 + nbt64, 256, 0, stream>>>(
          h_t, row_m, csr_m, h_m, wns, wrs, bs, a_m, NM, nbm64,
          h_m, row_t, csr_t, h_t, wnr, wrr, br, a_t, NT);
    } else {
      layer_k<false><<<nbm64 + nbt64, 256, 0, stream>>>(
          h_t, row_m, csr_m, h_m, wns, wrs, bs, a_m, NM, nbm64,
          h_m, row_t, csr_t, h_t, wnr, wrr, br, a_t, NT);
    }
    unsigned short* tmp;
    tmp = h_t; h_t = a_t; a_t = tmp;
    tmp = h_m; h_m = a_m; a_m = tmp;
  }

  classify_k<<<(Q + 7) / 8, 256, 0, stream>>>(h_t, h_m, qsrc, qdst, cls_w, cls_b,
                                              (float*)d_out, Q);
}

// Round 9
// 256.850 us; speedup vs baseline: 1.1132x; 1.1132x over previous
//
#include <hip/hip_runtime.h>
#include <cstdint>
#include <cstddef>

#define D 128
#define F_IN 256

typedef __attribute__((ext_vector_type(8))) short bf16x8;
typedef __attribute__((ext_vector_type(4))) float f32x4;

__device__ __forceinline__ unsigned short f2bs(float f) {
  unsigned int x = __builtin_bit_cast(unsigned int, f);
  x = x + 0x7fffu + ((x >> 16) & 1u);           // round-to-nearest-even
  return (unsigned short)(x >> 16);
}
__device__ __forceinline__ unsigned pk2(float lo, float hi) {
  return (unsigned)f2bs(lo) | ((unsigned)f2bs(hi) << 16);
}
__device__ __forceinline__ float b2f(unsigned int lo16) {
  unsigned int x = lo16 << 16;
  return __builtin_bit_cast(float, x);
}
__device__ __forceinline__ void gl_lds16v(const void* g, void* l) {
  __builtin_amdgcn_global_load_lds(
      (__attribute__((address_space(1))) void*)g,
      (__attribute__((address_space(3))) void*)l, 16, 0, 0);
}
__device__ __forceinline__ uint4 pack8(float4 a, float4 b) {
  uint4 o;
  o.x = pk2(a.x, a.y); o.y = pk2(a.z, a.w);
  o.z = pk2(b.x, b.y); o.w = pk2(b.z, b.w);
  return o;
}

// ================= prep: weight converts + prof gather + bucket histogram =================

__global__ __launch_bounds__(256) void prep_k(
    const float* __restrict__ s0, unsigned short* __restrict__ d0, int n0,
    const float* __restrict__ s1, unsigned short* __restrict__ d1, int n1,
    const float* __restrict__ s2, unsigned short* __restrict__ d2, int n2,
    const float* __restrict__ s3, unsigned short* __restrict__ d3, int n3,
    const float* __restrict__ s4, unsigned short* __restrict__ d4, int n4,
    int nbC,
    const float* __restrict__ emb, const int* __restrict__ ids,
    unsigned short* __restrict__ hm, int NM, int nbG,
    const int* __restrict__ esrc, const int* __restrict__ edst,
    int* __restrict__ bktT, int* __restrict__ bktM,
    int E, int SHT, int SHM, int nbA)
{
  int bid = blockIdx.x;
  int tid = threadIdx.x;
  if (bid < nbC) {
    int j = bid * 256 + tid;
    const float* s; unsigned short* d;
    if (j < n0) { s = s0; d = d0; }
    else {
      j -= n0;
      if (j < n1) { s = s1; d = d1; }
      else {
        j -= n1;
        if (j < n2) { s = s2; d = d2; }
        else {
          j -= n2;
          if (j < n3) { s = s3; d = d3; }
          else { j -= n3; if (j >= n4) return; s = s4; d = d4; }
        }
      }
    }
    const float4* sp = (const float4*)(s + (size_t)j * 8);
    *(uint4*)(d + (size_t)j * 8) = pack8(sp[0], sp[1]);
    return;
  }
  bid -= nbC;
  if (bid < nbG) {
    int i = bid * 256 + tid;
    if (i >= NM * 16) return;
    int r = i >> 4, c = (i & 15) * 8;
    const float* s = emb + (size_t)ids[r] * D + c;
    *(uint4*)(hm + (size_t)r * D + c) = pack8(*(const float4*)s, *(const float4*)(s + 4));
    return;
  }
  bid -= nbG;
  __shared__ int sh[256];
  sh[tid] = 0;
  __syncthreads();
  int stride = nbA * 256;
  for (int e = bid * 256 + tid; e < E; e += stride) {
    atomicAdd(&sh[esrc[e] >> SHT], 1);
    atomicAdd(&sh[128 + (edst[e] >> SHM)], 1);
  }
  __syncthreads();
  if (tid < 128) { if (sh[tid]) atomicAdd(&bktT[tid], sh[tid]); }
  else { if (sh[tid]) atomicAdd(&bktM[tid - 128], sh[tid]); }
}

// ================= A2: scan bucket counts -> bases + cursors =================

__global__ void a2_scan_k(const int* __restrict__ bktT, int* __restrict__ baseT, int* __restrict__ curT, int BT,
                          const int* __restrict__ bktM, int* __restrict__ baseM, int* __restrict__ curM, int BM) {
  __shared__ int sT[129], sM[129];
  int tid = threadIdx.x;
  if (tid < BT) sT[tid] = bktT[tid];
  if (tid < BM) sM[tid] = bktM[tid];
  __syncthreads();
  if (tid == 0) { int r = 0; for (int i = 0; i < BT; ++i) { int c = sT[i]; sT[i] = r; r += c; } sT[BT] = r; }
  if (tid == 1) { int r = 0; for (int i = 0; i < BM; ++i) { int c = sM[i]; sM[i] = r; r += c; } sM[BM] = r; }
  __syncthreads();
  if (tid <= BT) { baseT[tid] = sT[tid]; if (tid < BT) curT[tid] = sT[tid]; }
  if (tid <= BM) { baseM[tid] = sM[tid]; if (tid < BM) curM[tid] = sM[tid]; }
}

// ================= A3 body: multi-split partition with LDS staging =================

#define CH 4096

__device__ __forceinline__ void a3_body(
    const int* __restrict__ esrc, const int* __restrict__ edst,
    unsigned* __restrict__ partT, unsigned* __restrict__ partM,
    int* __restrict__ curT, int* __restrict__ curM,
    int E, int BT, int BM, int SHT, int SHM, int blk, char* smraw)
{
  unsigned* stT = (unsigned*)smraw;            // 4096
  unsigned* stM = stT + CH;                    // 4096
  int* hT  = (int*)(stM + CH);
  int* lbT = hT + 128;
  int* lcT = hT + 256;
  int* gbT = hT + 384;
  int* hM  = hT + 512;
  int* lbM = hT + 640;
  int* lcM = hT + 768;
  int* gbM = hT + 896;
  int* st2 = hT + 1024;                        // 256

  int tid = threadIdx.x;
  int c0 = blk * CH;
  int len = E - c0; if (len > CH) len = CH;

  if (tid < 128) { hT[tid] = 0; hM[tid] = 0; }
  __syncthreads();
  for (int i = tid; i < len; i += 256) {
    atomicAdd(&hT[esrc[c0 + i] >> SHT], 1);
    atomicAdd(&hM[edst[c0 + i] >> SHM], 1);
  }
  __syncthreads();
  int own = (tid < 128) ? hT[tid] : hM[tid - 128];
  st2[tid] = own;
  __syncthreads();
  for (int dd = 1; dd < 128; dd <<= 1) {
    int y = ((tid & 127) >= dd) ? st2[tid - dd] : 0;
    __syncthreads();
    st2[tid] += y;
    __syncthreads();
  }
  int excl = st2[tid] - own;
  if (tid < 128) { lbT[tid] = excl; lcT[tid] = excl; }
  else { lbM[tid - 128] = excl; lcM[tid - 128] = excl; }
  __syncthreads();
  if (tid < BT) { if (hT[tid]) gbT[tid] = atomicAdd(&curT[tid], hT[tid]); }
  if (tid >= 128 && tid - 128 < BM) { int m = tid - 128; if (hM[m]) gbM[m] = atomicAdd(&curM[m], hM[m]); }
  __syncthreads();
  for (int i = tid; i < len; i += 256) {
    unsigned s = (unsigned)esrc[c0 + i], dn = (unsigned)edst[c0 + i];
    int p = atomicAdd(&lcT[s >> SHT], 1);
    stT[p] = (s << 15) | dn;
    int q = atomicAdd(&lcM[dn >> SHM], 1);
    stM[q] = (dn << 17) | s;
  }
  __syncthreads();
  for (int b = 0; b < BT; ++b) {
    int cb = hT[b]; if (!cb) continue;
    int lb = lbT[b]; int gb = gbT[b];
    for (int i = tid; i < cb; i += 256) partT[gb + i] = stT[lb + i];
  }
  for (int b = 0; b < BM; ++b) {
    int cb = hM[b]; if (!cb) continue;
    int lb = lbM[b]; int gb = gbM[b];
    for (int i = tid; i < cb; i += 256) partM[gb + i] = stM[lb + i];
  }
}

// ================= encoder GEMM body (fp32 A staged raw, counted-vmcnt pipeline) =================

__device__ __forceinline__ void enc_body(
    const float* __restrict__ A, const unsigned short* __restrict__ W,
    const float* __restrict__ bias, unsigned short* __restrict__ out, int M,
    int blk, char* smraw)
{
  float* bufA0 = (float*)smraw;                              // [2][4096] f32
  unsigned short* bufW0 = (unsigned short*)(smraw + 32768);  // [2][4096] bf16
  const int tid = threadIdx.x;
  const int w = tid >> 6, l = tid & 63;
  const int wr = w >> 1, wc = w & 1;
  const int lr = l & 15, kg = l >> 4;
  const int row0 = blk * 128;
  const int arow = l >> 3;
  const int au = l & 7;
  const int wrow = l >> 2;
  const int wu = l & 3;

  f32x4 acc[4][4] = {};

  auto stage = [&](int st, int bsel) {
    int k0 = st * 32;
    float* bA = bufA0 + bsel * 4096;
    unsigned short* bW = bufW0 + bsel * 4096;
#pragma unroll
    for (int q = 0; q < 4; ++q) {
      int r = w * 32 + q * 8 + arow;
      int gr = row0 + r; if (gr >= M) gr = M - 1;
      int gu = au ^ (r & 7);
      gl_lds16v(A + (size_t)gr * F_IN + k0 + gu * 4, bA + (w * 32 + q * 8) * 32 + l * 4);
    }
#pragma unroll
    for (int q = 0; q < 2; ++q) {
      int r = w * 32 + q * 16 + wrow;
      int gu = wu ^ ((r >> 1) & 3);
      gl_lds16v(W + (size_t)r * F_IN + k0 + gu * 8, bW + (w * 32 + q * 16) * 32 + l * 8);
    }
  };

  stage(0, 0);
#pragma unroll 1
  for (int st = 0; st < F_IN / 32; ++st) {
    if (st < F_IN / 32 - 1) {
      stage(st + 1, (st + 1) & 1);
      __builtin_amdgcn_sched_barrier(0);
      asm volatile("s_waitcnt vmcnt(6)" ::: "memory");
    } else {
      __builtin_amdgcn_sched_barrier(0);
      asm volatile("s_waitcnt vmcnt(0)" ::: "memory");
    }
    __builtin_amdgcn_s_barrier();
    __builtin_amdgcn_sched_barrier(0);
    const float* bA = bufA0 + (st & 1) * 4096;
    const unsigned short* bW = bufW0 + (st & 1) * 4096;
    bf16x8 aF[4], bF[4];
#pragma unroll
    for (int i = 0; i < 4; ++i) {
      int r = wr * 64 + i * 16 + lr;
      const float4* pa = (const float4*)(bA + r * 32);
      float4 v0 = pa[(2 * kg) ^ (r & 7)];
      float4 v1 = pa[(2 * kg + 1) ^ (r & 7)];
      uint4 c = pack8(v0, v1);
      aF[i] = *(bf16x8*)&c;
    }
#pragma unroll
    for (int j = 0; j < 4; ++j) {
      int r = wc * 64 + j * 16 + lr;
      bF[j] = *(const bf16x8*)&bW[r * 32 + ((kg ^ ((r >> 1) & 3)) * 8)];
    }
#pragma unroll
    for (int i = 0; i < 4; ++i)
#pragma unroll
      for (int j = 0; j < 4; ++j)
        acc[i][j] = __builtin_amdgcn_mfma_f32_16x16x32_bf16(aF[i], bF[j], acc[i][j], 0, 0, 0);
    __builtin_amdgcn_sched_barrier(0);
    __builtin_amdgcn_s_barrier();
  }

  __syncthreads();
  float bn[4];
#pragma unroll
  for (int j = 0; j < 4; ++j) bn[j] = bias[wc * 64 + j * 16 + lr];
  unsigned short* ow = (unsigned short*)smraw + w * 4096;
#pragma unroll
  for (int i = 0; i < 4; ++i)
#pragma unroll
    for (int j = 0; j < 4; ++j) {
      f32x4 v = acc[i][j];
#pragma unroll
      for (int r = 0; r < 4; ++r)
        ow[(i * 16 + kg * 4 + r) * 64 + j * 16 + lr] = f2bs(v[r] + bn[j]);
    }
  __syncthreads();
#pragma unroll
  for (int q = 0; q < 8; ++q) {
    int u = q * 64 + l;
    int lrow = u >> 3;
    int cu = (u & 7) * 8;
    int gr = row0 + wr * 64 + lrow;
    if (gr < M)
      *(uint4*)(out + (size_t)gr * D + wc * 64 + cu) = *(const uint4*)&ow[lrow * 64 + cu];
  }
}

// merged: a3 partition blocks + encoder GEMM blocks in one dispatch
__global__ __launch_bounds__(256) void a3enc_k(
    const int* __restrict__ esrc, const int* __restrict__ edst,
    unsigned* __restrict__ partT, unsigned* __restrict__ partM,
    int* __restrict__ curT, int* __restrict__ curM,
    int E, int BT, int BM, int SHT, int SHM, int nbA3,
    const float* __restrict__ A, const unsigned short* __restrict__ W,
    const float* __restrict__ bias, unsigned short* __restrict__ out, int M)
{
  __shared__ char smraw[49152];
  if ((int)blockIdx.x < nbA3)
    a3_body(esrc, edst, partT, partM, curT, curM, E, BT, BM, SHT, SHM, blockIdx.x, smraw);
  else
    enc_body(A, W, bias, out, M, blockIdx.x - nbA3, smraw);
}

// ================= B: per-bucket CSR finalize (rowptr, csr) =================

#define BCAP 12288

__global__ __launch_bounds__(256) void b_csr_k(
    const unsigned* __restrict__ partT, const int* __restrict__ baseT,
    int* __restrict__ rowT, int* __restrict__ csrT, int NT, int BT, int SHT,
    const unsigned* __restrict__ partM, const int* __restrict__ baseM,
    int* __restrict__ rowM, int* __restrict__ csrM, int NM, int BM, int SHM, int E)
{
  __shared__ int cnt[1024];
  __shared__ int st[256];
  __shared__ unsigned stage[BCAP];

  const unsigned* part; const int* base; int* row; int* csr;
  int N, SH, KS; unsigned PM; int b; bool last;
  if ((int)blockIdx.x < BT) {
    part = partT; base = baseT; row = rowT; csr = csrT;
    N = NT; SH = SHT; KS = 15; PM = 0x7fffu; b = blockIdx.x; last = (b == BT - 1);
  } else {
    part = partM; base = baseM; row = rowM; csr = csrM;
    N = NM; SH = SHM; KS = 17; PM = 0x1ffffu; b = blockIdx.x - BT; last = (b == BM - 1);
  }
  int tid = threadIdx.x;
  int ebeg = base[b], eend = base[b + 1];
  int tot = eend - ebeg;
  int n0 = b << SH;
  int width = 1 << SH;
  int nw = N - n0; if (nw > width) nw = width;
  int seg = (width + 255) >> 8;

  for (int j = 0; j < seg; ++j) { int idx = tid * seg + j; if (idx < nw) cnt[idx] = 0; }
  __syncthreads();
  for (int i = tid; i < tot; i += 256) {
    int k = (int)(part[ebeg + i] >> KS) - n0;
    atomicAdd(&cnt[k], 1);
  }
  __syncthreads();
  int s = 0;
  for (int j = 0; j < seg; ++j) { int idx = tid * seg + j; if (idx < nw) s += cnt[idx]; }
  st[tid] = s;
  __syncthreads();
  for (int dd = 1; dd < 256; dd <<= 1) {
    int y = (tid >= dd) ? st[tid - dd] : 0;
    __syncthreads();
    st[tid] += y;
    __syncthreads();
  }
  int run = st[tid] - s;
  for (int j = 0; j < seg; ++j) {
    int idx = tid * seg + j;
    if (idx < nw) {
      int c = cnt[idx];
      row[n0 + idx] = ebeg + run;
      cnt[idx] = run;
      run += c;
    }
  }
  if (last && tid == 0) row[N] = E;
  __syncthreads();
  if (tot <= BCAP) {
    for (int i = tid; i < tot; i += 256) {
      unsigned p = part[ebeg + i];
      int k = (int)(p >> KS) - n0;
      int pos = atomicAdd(&cnt[k], 1);
      stage[pos] = p & PM;
    }
    __syncthreads();
    for (int i = tid; i < tot; i += 256) csr[ebeg + i] = (int)stage[i];
  } else {
    for (int i = tid; i < tot; i += 256) {
      unsigned p = part[ebeg + i];
      int k = (int)(p >> KS) - n0;
      int pos = atomicAdd(&cnt[k], 1);
      csr[ebeg + pos] = (int)(p & PM);
    }
  }
}

// ================= aggregation: paired-row gathers, 1 node per 32-lane group =================
// Each uint4 load fetches TWO 256B rows per 32-group (lanes 0-15 edge 2u, 16-31 edge 2u+1);
// one 8-load batch covers 16 edges. Final shfl_xor(16) folds the halves.

__global__ __launch_bounds__(256) void aggregate3_k(
    const unsigned short* __restrict__ tabM, const int* __restrict__ rowpM,
    const int* __restrict__ idxM, unsigned short* __restrict__ outM, int nM, int nblkM,
    const unsigned short* __restrict__ tabT, const int* __restrict__ rowpT,
    const int* __restrict__ idxT, unsigned short* __restrict__ outT, int nT)
{
  const unsigned short* tab; const int* rowp; const int* idx;
  unsigned short* outp; int n, nodeb;
  if ((int)blockIdx.x < nblkM) {
    tab = tabM; rowp = rowpM; idx = idxM; outp = outM; n = nM;
    nodeb = blockIdx.x * 8;
  } else {
    tab = tabT; rowp = rowpT; idx = idxT; outp = outT; n = nT;
    nodeb = (blockIdx.x - nblkM) * 8;
  }
  const int tid = threadIdx.x;
  const int l = tid & 63;
  const int sub = l >> 5;            // which node within the wave
  const int half = (l >> 4) & 1;     // even/odd edge stream
  const int l16 = l & 15;            // 16B column unit
  const int node = nodeb + (tid >> 6) * 2 + sub;
  const int nodeC = node < n ? node : n - 1;
  int b = rowp[nodeC];
  int e = rowp[nodeC + 1];
  if (node >= n) e = b;
  const int deg = e - b;
  int nb = (deg + 15) >> 4;
  int onb = __shfl_xor(nb, 32, 64);
  int trip = nb > onb ? nb : onb;
  const unsigned short* tl = tab + l16 * 8;

  float a0 = 0.f, a1 = 0.f, a2 = 0.f, a3 = 0.f;
  float a4 = 0.f, a5 = 0.f, a6 = 0.f, a7 = 0.f;
  for (int t = 0; t < trip; ++t) {
    int base = b + t * 16 + half;
    int pp[8]; bool ok[8];
#pragma unroll
    for (int u = 0; u < 8; ++u) {
      int p = base + 2 * u;
      ok[u] = p < e;
      pp[u] = ok[u] ? idx[p] : 0;
    }
    uint4 vv[8];
#pragma unroll
    for (int u = 0; u < 8; ++u) {
      uint4 z; z.x = 0u; z.y = 0u; z.z = 0u; z.w = 0u;
      vv[u] = z;
      if (ok[u]) vv[u] = *(const uint4*)(tl + (size_t)pp[u] * D);
    }
#pragma unroll
    for (int u = 0; u < 8; ++u) {
      a0 += b2f(vv[u].x & 0xffffu); a1 += b2f(vv[u].x >> 16);
      a2 += b2f(vv[u].y & 0xffffu); a3 += b2f(vv[u].y >> 16);
      a4 += b2f(vv[u].z & 0xffffu); a5 += b2f(vv[u].z >> 16);
      a6 += b2f(vv[u].w & 0xffffu); a7 += b2f(vv[u].w >> 16);
    }
  }
  a0 += __shfl_xor(a0, 16, 64);
  a1 += __shfl_xor(a1, 16, 64);
  a2 += __shfl_xor(a2, 16, 64);
  a3 += __shfl_xor(a3, 16, 64);
  a4 += __shfl_xor(a4, 16, 64);
  a5 += __shfl_xor(a5, 16, 64);
  a6 += __shfl_xor(a6, 16, 64);
  a7 += __shfl_xor(a7, 16, 64);
  if (node < n && half == 0) {
    float inv = 1.0f / (float)(deg > 1 ? deg : 1);
    uint4 o;
    o.x = pk2(a0 * inv, a1 * inv);
    o.y = pk2(a2 * inv, a3 * inv);
    o.z = pk2(a4 * inv, a5 * inv);
    o.w = pk2(a6 * inv, a7 * inv);
    *(uint4*)(outp + (size_t)node * D + l16 * 8) = o;
  }
}

// ================= bf16 MFMA fused dual GEMM (2-phase pipeline, swizzled LDS) =================

template<bool RELU>
__device__ __forceinline__ void gemm_body(
    const unsigned short* __restrict__ Aop, const unsigned short* __restrict__ WA,
    const unsigned short* __restrict__ Bop, const unsigned short* __restrict__ WB,
    const float* __restrict__ bias, unsigned short* __restrict__ out, int M,
    int blk, char* smraw)
{
  unsigned short* bufA0 = (unsigned short*)smraw;            // [2][4096]
  unsigned short* bufW0 = (unsigned short*)(smraw + 16384);  // [2][4096]
  const int tid = threadIdx.x;
  const int w = tid >> 6, l = tid & 63;
  const int wr = w >> 1, wc = w & 1;
  const int lr = l & 15, kg = l >> 4;
  const int row0 = blk * 128;
  const int srow = l >> 2;   // 0..15
  const int su = l & 3;      // 16B unit

  f32x4 acc[4][4] = {};

  auto stage = [&](int st, int bsel) {
    const unsigned short* Ap = (st < 4) ? Aop : Bop;
    const unsigned short* Wp = (st < 4) ? WA : WB;
    int k0 = (st & 3) * 32;
    unsigned short* bA = bufA0 + bsel * 4096;
    unsigned short* bW = bufW0 + bsel * 4096;
#pragma unroll
    for (int q = 0; q < 2; ++q) {
      int r = w * 32 + q * 16 + srow;
      int gr = row0 + r; if (gr >= M) gr = M - 1;   // clamp: keeps vmcnt counts uniform
      int gu = su ^ ((r >> 1) & 3);
      gl_lds16v(Ap + (size_t)gr * D + k0 + gu * 8, bA + (w * 32 + q * 16) * 32 + l * 8);
      gl_lds16v(Wp + (size_t)r * D + k0 + gu * 8, bW + (w * 32 + q * 16) * 32 + l * 8);
    }
  };

  stage(0, 0);
#pragma unroll 1
  for (int st = 0; st < 8; ++st) {
    if (st < 7) {
      stage(st + 1, (st + 1) & 1);
      __builtin_amdgcn_sched_barrier(0);
      asm volatile("s_waitcnt vmcnt(4)" ::: "memory");
    } else {
      __builtin_amdgcn_sched_barrier(0);
      asm volatile("s_waitcnt vmcnt(0)" ::: "memory");
    }
    __builtin_amdgcn_s_barrier();
    __builtin_amdgcn_sched_barrier(0);
    const unsigned short* bA = bufA0 + (st & 1) * 4096;
    const unsigned short* bW = bufW0 + (st & 1) * 4096;
    bf16x8 aF[4], bF[4];
#pragma unroll
    for (int i = 0; i < 4; ++i) {
      int r = wr * 64 + i * 16 + lr;
      aF[i] = *(const bf16x8*)&bA[r * 32 + ((kg ^ ((r >> 1) & 3)) * 8)];
    }
#pragma unroll
    for (int j = 0; j < 4; ++j) {
      int r = wc * 64 + j * 16 + lr;
      bF[j] = *(const bf16x8*)&bW[r * 32 + ((kg ^ ((r >> 1) & 3)) * 8)];
    }
#pragma unroll
    for (int i = 0; i < 4; ++i)
#pragma unroll
      for (int j = 0; j < 4; ++j)
        acc[i][j] = __builtin_amdgcn_mfma_f32_16x16x32_bf16(aF[i], bF[j], acc[i][j], 0, 0, 0);
    __builtin_amdgcn_sched_barrier(0);
    __builtin_amdgcn_s_barrier();
  }

  __syncthreads();
  float bn[4];
#pragma unroll
  for (int j = 0; j < 4; ++j) bn[j] = bias[wc * 64 + j * 16 + lr];
  unsigned short* ow = (unsigned short*)smraw + w * 4096;
#pragma unroll
  for (int i = 0; i < 4; ++i)
#pragma unroll
    for (int j = 0; j < 4; ++j) {
      f32x4 v = acc[i][j];
#pragma unroll
      for (int r = 0; r < 4; ++r) {
        float x = v[r] + bn[j];
        if (RELU) x = fmaxf(x, 0.f);
        ow[(i * 16 + kg * 4 + r) * 64 + j * 16 + lr] = f2bs(x);
      }
    }
  __syncthreads();
#pragma unroll
  for (int q = 0; q < 8; ++q) {
    int u = q * 64 + l;
    int lrow = u >> 3;
    int cu = (u & 7) * 8;
    int gr = row0 + wr * 64 + lrow;
    if (gr < M)
      *(uint4*)(out + (size_t)gr * D + wc * 64 + cu) = *(const uint4*)&ow[lrow * 64 + cu];
  }
}

template<bool RELU>
__global__ __launch_bounds__(256) void gemm_pair_k(
    const unsigned short* __restrict__ Am, const unsigned short* __restrict__ WAm,
    const unsigned short* __restrict__ Bm, const unsigned short* __restrict__ WBm,
    const float* __restrict__ biasm, unsigned short* __restrict__ outm, int Mm, int nbm,
    const unsigned short* __restrict__ At, const unsigned short* __restrict__ WAt,
    const unsigned short* __restrict__ Bt, const unsigned short* __restrict__ WBt,
    const float* __restrict__ biast, unsigned short* __restrict__ outt, int Mt)
{
  __shared__ char smraw[32768];
  if ((int)blockIdx.x < nbm)
    gemm_body<RELU>(Am, WAm, Bm, WBm, biasm, outm, Mm, blockIdx.x, smraw);
  else
    gemm_body<RELU>(At, WAt, Bt, WBt, biast, outt, Mt, blockIdx.x - nbm, smraw);
}

// ================= classifier =================

__global__ __launch_bounds__(256) void classify_k(
    const unsigned short* __restrict__ ht, const unsigned short* __restrict__ hm,
    const int* __restrict__ qs, const int* __restrict__ qd,
    const float* __restrict__ w, const float* __restrict__ bptr,
    float* __restrict__ out, int Q)
{
  int g = blockIdx.x * 8 + (threadIdx.x >> 5);
  if (g >= Q) return;
  int l = threadIdx.x & 31;
  const unsigned short* src = (l < 16)
      ? ht + (size_t)qs[g] * D + l * 8
      : hm + (size_t)qd[g] * D + (l - 16) * 8;
  uint4 v = *(const uint4*)src;
  const float* wp = w + l * 8;
  float acc = 0.f;
  acc += b2f(v.x & 0xffffu) * wp[0];
  acc += b2f(v.x >> 16)     * wp[1];
  acc += b2f(v.y & 0xffffu) * wp[2];
  acc += b2f(v.y >> 16)     * wp[3];
  acc += b2f(v.z & 0xffffu) * wp[4];
  acc += b2f(v.z >> 16)     * wp[5];
  acc += b2f(v.w & 0xffffu) * wp[6];
  acc += b2f(v.w >> 16)     * wp[7];
#pragma unroll
  for (int m = 16; m >= 1; m >>= 1) acc += __shfl_xor(acc, m, 64);
  if (l == 0) out[g] = acc + bptr[0];
}

// ================= launcher =================

extern "C" void kernel_launch(void* const* d_in, const int* in_sizes, int n_in,
                              void* d_out, int out_size, void* d_ws, size_t ws_size,
                              hipStream_t stream)
{
  const float* x_thesis = (const float*)d_in[0];
  const int*   mentor_id = (const int*)d_in[1];
  const int*   esrc = (const int*)d_in[2];
  const int*   edst = (const int*)d_in[3];
  const int*   qsrc = (const int*)d_in[4];
  const int*   qdst = (const int*)d_in[5];
  const float* lin_w = (const float*)d_in[6];
  const float* lin_b = (const float*)d_in[7];
  const float* prof  = (const float*)d_in[8];
  const float* Wn_sup = (const float*)d_in[9];
  const float* Wr_sup = (const float*)d_in[10];
  const float* b_sup  = (const float*)d_in[11];
  const float* Wn_rev = (const float*)d_in[12];
  const float* Wr_rev = (const float*)d_in[13];
  const float* b_rev  = (const float*)d_in[14];
  const float* cls_w  = (const float*)d_in[15];
  const float* cls_b  = (const float*)d_in[16];

  const int NT = in_sizes[0] / F_IN;
  const int NM = in_sizes[1];
  const int E  = in_sizes[2];
  const int Q  = in_sizes[4];
  const int L  = in_sizes[11] / D;

  int SHT = 0; while ((((NT - 1) >> SHT) + 1) > 128) ++SHT;
  int SHM = 0; while ((((NM - 1) >> SHM) + 1) > 128) ++SHM;
  const int BT = ((NT - 1) >> SHT) + 1;
  const int BM = ((NM - 1) >> SHM) + 1;

  char* wsb = (char*)d_ws;
  size_t off = 0;
  auto alloc = [&](size_t bytes) {
    void* p = wsb + off;
    off = (off + bytes + 255) & ~(size_t)255;
    return p;
  };
  unsigned short* h_t   = (unsigned short*)alloc((size_t)NT * D * 2);
  unsigned short* a_t   = (unsigned short*)alloc((size_t)NT * D * 2);
  unsigned short* h_m   = (unsigned short*)alloc((size_t)NM * D * 2);
  unsigned short* a_m   = (unsigned short*)alloc((size_t)NM * D * 2);
  unsigned short* linw_bf = (unsigned short*)alloc((size_t)D * F_IN * 2);
  unsigned short* wns_bf  = (unsigned short*)alloc((size_t)L * D * D * 2);
  unsigned short* wrs_bf  = (unsigned short*)alloc((size_t)L * D * D * 2);
  unsigned short* wnr_bf  = (unsigned short*)alloc((size_t)L * D * D * 2);
  unsigned short* wrr_bf  = (unsigned short*)alloc((size_t)L * D * D * 2);
  int* row_t = (int*)alloc(((size_t)NT + 1) * 4);
  int* row_m = (int*)alloc(((size_t)NM + 1) * 4);
  int* csr_t = (int*)alloc((size_t)E * 4);
  int* csr_m = (int*)alloc((size_t)E * 4);
  unsigned* partT = (unsigned*)alloc((size_t)E * 4);
  unsigned* partM = (unsigned*)alloc((size_t)E * 4);
  size_t bkt_off = off;
  int* bktT  = (int*)alloc(128 * 4);
  int* bktM  = (int*)alloc(128 * 4);
  size_t bkt_end = off;
  int* baseT = (int*)alloc(129 * 4);
  int* baseM = (int*)alloc(129 * 4);
  int* curT  = (int*)alloc(128 * 4);
  int* curM  = (int*)alloc(128 * 4);
  (void)n_in; (void)out_size; (void)ws_size;

  (void)hipMemsetAsync(wsb + bkt_off, 0, bkt_end - bkt_off, stream);

  {
    int n0 = D * F_IN / 8, nw = L * D * D / 8;
    int totc = n0 + 4 * nw;
    int nbC = (totc + 255) / 256;
    int nbG = (NM * 16 + 255) / 256;
    int nbA = 256;
    prep_k<<<nbC + nbG + nbA, 256, 0, stream>>>(
        lin_w, linw_bf, n0, Wn_sup, wns_bf, nw, Wr_sup, wrs_bf, nw,
        Wn_rev, wnr_bf, nw, Wr_rev, wrr_bf, nw, nbC,
        prof, mentor_id, h_m, NM, nbG,
        esrc, edst, bktT, bktM, E, SHT, SHM, nbA);
  }
  a2_scan_k<<<1, 256, 0, stream>>>(bktT, baseT, curT, BT, bktM, baseM, curM, BM);

  int nbA3 = (E + CH - 1) / CH;
  int nbEnc = (NT + 127) / 128;
  a3enc_k<<<nbA3 + nbEnc, 256, 0, stream>>>(
      esrc, edst, partT, partM, curT, curM, E, BT, BM, SHT, SHM, nbA3,
      x_thesis, linw_bf, lin_b, h_t, NT);

  b_csr_k<<<BT + BM, 256, 0, stream>>>(
      partT, baseT, row_t, csr_t, NT, BT, SHT,
      partM, baseM, row_m, csr_m, NM, BM, SHM, E);

  int agg_nbm = (NM + 7) / 8, agg_nbt = (NT + 7) / 8;
  int gem_nbm = (NM + 127) / 128, gem_nbt = (NT + 127) / 128;
  for (int l = 0; l < L; ++l) {
    aggregate3_k<<<agg_nbm + agg_nbt, 256, 0, stream>>>(
        h_t, row_m, csr_m, a_m, NM, agg_nbm,
        h_m, row_t, csr_t, a_t, NT);

    const unsigned short* wns = wns_bf + (size_t)l * D * D;
    const unsigned short* wrs = wrs_bf + (size_t)l * D * D;
    const unsigned short* wnr = wnr_bf + (size_t)l * D * D;
    const unsigned short* wrr = wrr_bf + (size_t)l * D * D;
    const float* bs = b_sup + (size_t)l * D;
    const float* br = b_rev + (size_t)l * D;
    if (l < L - 1) {
      gemm_pair_k<true><<<gem_nbm + gem_nbt, 256, 0, stream>>>(
          a_m, wns, h_m, wrs, bs, a_m, NM, gem_nbm,
          a_t, wnr, h_t, wrr, br, a_t, NT);
    } else {
      gemm_pair_k<false><<<gem_nbm + gem_nbt, 256, 0, stream>>>(
          a_m, wns, h_m, wrs, bs, a_m, NM, gem_nbm,
          a_t, wnr, h_t, wrr, br, a_t, NT);
    }
    unsigned short* tmp;
    tmp = h_t; h_t = a_t; a_t = tmp;
    tmp = h_m; h_m = a_m; a_m = tmp;
  }

  classify_k<<<(Q + 7) / 8, 256, 0, stream>>>(h_t, h_m, qsrc, qdst, cls_w, cls_b,
                                              (float*)d_out, Q);
}